// Round 1
// baseline (835.824 us; speedup 1.0000x reference)
//
#include <hip/hip_runtime.h>
#include <hip/hip_bf16.h>
#include <stdint.h>

#define NN 50000
#define EE 800000
#define DD 64
#define RR 10
#define BB 4

using u16 = unsigned short;
using u32 = unsigned int;

__device__ __forceinline__ u32 f2bf_rn(float x) {
    u32 u = __float_as_uint(x);
    return (u + 0x7FFFu + ((u >> 16) & 1u)) >> 16;
}

// Transform: block = 256 threads handles 128 nodes x 64 outs for relation
// r = blockIdx.y + rbase. r < RR: write bf16 row into xr[r*NN + n].
// r == RR: W = self_loop_weight, write fp32 into out (this also overwrites the
// 0xAA poison so the edge kernel can atomically accumulate on top).
__global__ __launch_bounds__(256, 3)
void k_transform(const float* __restrict__ feat,
                 const float* __restrict__ weight,
                 const float* __restrict__ w_comp,
                 const float* __restrict__ self_w,
                 u16* __restrict__ xr,
                 float* __restrict__ out,
                 int rbase) {
    __shared__ float sW[DD * DD];       // 16 KB
    __shared__ float sF[128 * 68];      // 34.8 KB, stride 68 floats (16B-aligned rows, banks spread)
    const int t = threadIdx.x;
    const int r = blockIdx.y + rbase;
    const int nbase = blockIdx.x * 128;

    // --- stage W[r] into LDS (basis combination, or self-loop weight) ---
    if (r < RR) {
        const float c0 = w_comp[r * BB + 0];
        const float c1 = w_comp[r * BB + 1];
        const float c2 = w_comp[r * BB + 2];
        const float c3 = w_comp[r * BB + 3];
        #pragma unroll
        for (int q = 0; q < 16; ++q) {
            int f = t + 256 * q;
            sW[f] = c0 * weight[f] + c1 * weight[4096 + f] +
                    c2 * weight[8192 + f] + c3 * weight[12288 + f];
        }
    } else {
        #pragma unroll
        for (int q = 0; q < 16; ++q) {
            int f = t + 256 * q;
            sW[f] = self_w[f];
        }
    }

    // --- stage feat tile: 128 rows x 64 cols, coalesced float4 loads ---
    #pragma unroll
    for (int q = 0; q < 8; ++q) {
        int f4 = q * 256 + t;          // 0..2047
        int nl = f4 >> 4;              // node-local 0..127
        int ic = (f4 & 15) << 2;       // col 0,4,...,60
        int n = nbase + nl;
        float4 v = make_float4(0.f, 0.f, 0.f, 0.f);
        if (n < NN) v = reinterpret_cast<const float4*>(feat)[(size_t)n * 16 + (f4 & 15)];
        *reinterpret_cast<float4*>(&sF[nl * 68 + ic]) = v;
    }
    __syncthreads();

    const int to = t & 7;    // o-group: covers o = to*4..to*4+3 and 32+to*4..32+to*4+3
    const int tn = t >> 3;   // 0..31; nodes tn + 32*j, j=0..3

    float acc[4][8];
    #pragma unroll
    for (int j = 0; j < 4; ++j)
        #pragma unroll
        for (int m = 0; m < 8; ++m) acc[j][m] = 0.f;

    #pragma unroll 4
    for (int i0 = 0; i0 < DD; i0 += 4) {
        float wv[4][8];
        #pragma unroll
        for (int k = 0; k < 4; ++k) {
            float4 a = *reinterpret_cast<const float4*>(&sW[(i0 + k) * DD + to * 4]);
            float4 b = *reinterpret_cast<const float4*>(&sW[(i0 + k) * DD + 32 + to * 4]);
            wv[k][0] = a.x; wv[k][1] = a.y; wv[k][2] = a.z; wv[k][3] = a.w;
            wv[k][4] = b.x; wv[k][5] = b.y; wv[k][6] = b.z; wv[k][7] = b.w;
        }
        #pragma unroll
        for (int j = 0; j < 4; ++j) {
            float4 f = *reinterpret_cast<const float4*>(&sF[(tn + 32 * j) * 68 + i0]);
            float fv[4] = {f.x, f.y, f.z, f.w};
            #pragma unroll
            for (int k = 0; k < 4; ++k)
                #pragma unroll
                for (int m = 0; m < 8; ++m)
                    acc[j][m] = fmaf(fv[k], wv[k][m], acc[j][m]);
        }
    }

    // --- epilogue ---
    if (r < RR) {
        #pragma unroll
        for (int j = 0; j < 4; ++j) {
            int n = nbase + tn + 32 * j;
            if (n < NN) {
                size_t row = ((size_t)r * NN + n) * DD;
                u32 p0 = f2bf_rn(acc[j][0]) | (f2bf_rn(acc[j][1]) << 16);
                u32 p1 = f2bf_rn(acc[j][2]) | (f2bf_rn(acc[j][3]) << 16);
                u32 p2 = f2bf_rn(acc[j][4]) | (f2bf_rn(acc[j][5]) << 16);
                u32 p3 = f2bf_rn(acc[j][6]) | (f2bf_rn(acc[j][7]) << 16);
                *reinterpret_cast<uint2*>(&xr[row + to * 4]) = make_uint2(p0, p1);
                *reinterpret_cast<uint2*>(&xr[row + 32 + to * 4]) = make_uint2(p2, p3);
            }
        }
    } else {
        #pragma unroll
        for (int j = 0; j < 4; ++j) {
            int n = nbase + tn + 32 * j;
            if (n < NN) {
                size_t row = (size_t)n * DD;
                *reinterpret_cast<float4*>(&out[row + to * 4]) =
                    make_float4(acc[j][0], acc[j][1], acc[j][2], acc[j][3]);
                *reinterpret_cast<float4*>(&out[row + 32 + to * 4]) =
                    make_float4(acc[j][4], acc[j][5], acc[j][6], acc[j][7]);
            }
        }
    }
}

// Edge gather+scatter: 16 threads per edge, each handles 4 outputs.
__global__ __launch_bounds__(256)
void k_edges(const int* __restrict__ src, const int* __restrict__ dst,
             const int* __restrict__ etype, const float* __restrict__ norm,
             const u16* __restrict__ xr, float* __restrict__ out) {
    int gtid = blockIdx.x * 256 + threadIdx.x;
    int e = gtid >> 4;
    int l = gtid & 15;
    if (e >= EE) return;
    int s = src[e];
    int d = dst[e];
    int rt = etype[e];
    float nm = norm[e];
    size_t row = ((size_t)rt * NN + s) * DD;
    uint2 u = *reinterpret_cast<const uint2*>(&xr[row + l * 4]);
    float f0 = __uint_as_float((u.x & 0xFFFFu) << 16);
    float f1 = __uint_as_float(u.x & 0xFFFF0000u);
    float f2 = __uint_as_float((u.y & 0xFFFFu) << 16);
    float f3 = __uint_as_float(u.y & 0xFFFF0000u);
    float* op = out + (size_t)d * DD + l * 4;
    atomicAdd(op + 0, f0 * nm);
    atomicAdd(op + 1, f1 * nm);
    atomicAdd(op + 2, f2 * nm);
    atomicAdd(op + 3, f3 * nm);
}

// Fallback (ws too small for xr): per-edge direct matvec, one wave per edge.
__global__ void k_makeW(const float* __restrict__ weight,
                        const float* __restrict__ w_comp,
                        float* __restrict__ W) {
    int f = blockIdx.x * 256 + threadIdx.x;
    if (f >= RR * 4096) return;
    int r = f >> 12;
    int io = f & 4095;
    float v = 0.f;
    #pragma unroll
    for (int b = 0; b < BB; ++b) v += w_comp[r * BB + b] * weight[b * 4096 + io];
    W[f] = v;
}

__global__ __launch_bounds__(256)
void k_edges_direct(const int* __restrict__ src, const int* __restrict__ dst,
                    const int* __restrict__ etype, const float* __restrict__ norm,
                    const float* __restrict__ feat, const float* __restrict__ W,
                    float* __restrict__ out) {
    int gtid = blockIdx.x * 256 + threadIdx.x;
    int e = gtid >> 6;
    int lane = gtid & 63;
    if (e >= EE) return;
    int s = src[e];
    int d = dst[e];
    int rt = etype[e];
    float nm = norm[e];
    const float* fr = feat + (size_t)s * DD;
    const float* Wr = W + (size_t)rt * 4096;
    float acc = 0.f;
    #pragma unroll
    for (int i = 0; i < DD; ++i) acc = fmaf(fr[i], Wr[i * DD + lane], acc);
    atomicAdd(&out[(size_t)d * DD + lane], acc * nm);
}

__global__ __launch_bounds__(256)
void k_relu(float* __restrict__ out) {
    int i = blockIdx.x * 256 + threadIdx.x;   // one float4 each, 800000 total
    float4* p = reinterpret_cast<float4*>(out);
    float4 v = p[i];
    v.x = fmaxf(v.x, 0.f);
    v.y = fmaxf(v.y, 0.f);
    v.z = fmaxf(v.z, 0.f);
    v.w = fmaxf(v.w, 0.f);
    p[i] = v;
}

extern "C" void kernel_launch(void* const* d_in, const int* in_sizes, int n_in,
                              void* d_out, int out_size, void* d_ws, size_t ws_size,
                              hipStream_t stream) {
    const float* feat   = (const float*)d_in[0];
    const int*   src    = (const int*)d_in[1];
    const int*   dst    = (const int*)d_in[2];
    const int*   etype  = (const int*)d_in[3];
    const float* norm   = (const float*)d_in[4];
    const float* weight = (const float*)d_in[5];
    const float* w_comp = (const float*)d_in[6];
    const float* self_w = (const float*)d_in[7];
    float* out = (float*)d_out;

    const size_t xr_bytes = (size_t)RR * NN * DD * sizeof(u16);  // 64 MB
    dim3 blk(256);

    if (ws_size >= xr_bytes) {
        u16* xr = (u16*)d_ws;
        // 391 node-tiles x 11 "relations" (r=10 is the self-loop -> writes d_out)
        k_transform<<<dim3(391, RR + 1), blk, 0, stream>>>(feat, weight, w_comp,
                                                           self_w, xr, out, 0);
        k_edges<<<dim3(EE * 16 / 256), blk, 0, stream>>>(src, dst, etype, norm, xr, out);
    } else {
        // Fallback: self-loop into d_out, then direct per-edge matvec.
        k_transform<<<dim3(391, 1), blk, 0, stream>>>(feat, weight, w_comp,
                                                      self_w, (u16*)d_ws, out, RR);
        float* W = (float*)d_ws;   // needs 160 KB
        k_makeW<<<dim3(160), blk, 0, stream>>>(weight, w_comp, W);
        k_edges_direct<<<dim3(EE * 64 / 256), blk, 0, stream>>>(src, dst, etype, norm,
                                                                feat, W, out);
    }
    k_relu<<<dim3(NN * DD / 4 / 256), blk, 0, stream>>>(out);
}

// Round 2
// 295.149 us; speedup vs baseline: 2.8319x; 2.8319x over previous
//
#include <hip/hip_runtime.h>
#include <hip/hip_bf16.h>
#include <stdint.h>

#define NN 50000
#define EE 800000
#define DD 64
#define RR 10
#define BB 4
#define NPAD 50176          // 196*256, padded node count for scan
#define NBLK 196

using u16 = unsigned short;
using u32 = unsigned int;

__device__ __forceinline__ u32 f2bf_rn(float x) {
    u32 u = __float_as_uint(x);
    return (u + 0x7FFFu + ((u >> 16) & 1u)) >> 16;
}

// ---------------- transform (unchanged from R1, passing) ----------------
__global__ __launch_bounds__(256, 3)
void k_transform(const float* __restrict__ feat,
                 const float* __restrict__ weight,
                 const float* __restrict__ w_comp,
                 const float* __restrict__ self_w,
                 u16* __restrict__ xr,
                 float* __restrict__ out,
                 int rbase) {
    __shared__ float sW[DD * DD];
    __shared__ float sF[128 * 68];
    const int t = threadIdx.x;
    const int r = blockIdx.y + rbase;
    const int nbase = blockIdx.x * 128;

    if (r < RR) {
        const float c0 = w_comp[r * BB + 0];
        const float c1 = w_comp[r * BB + 1];
        const float c2 = w_comp[r * BB + 2];
        const float c3 = w_comp[r * BB + 3];
        #pragma unroll
        for (int q = 0; q < 16; ++q) {
            int f = t + 256 * q;
            sW[f] = c0 * weight[f] + c1 * weight[4096 + f] +
                    c2 * weight[8192 + f] + c3 * weight[12288 + f];
        }
    } else {
        #pragma unroll
        for (int q = 0; q < 16; ++q) {
            int f = t + 256 * q;
            sW[f] = self_w[f];
        }
    }

    #pragma unroll
    for (int q = 0; q < 8; ++q) {
        int f4 = q * 256 + t;
        int nl = f4 >> 4;
        int ic = (f4 & 15) << 2;
        int n = nbase + nl;
        float4 v = make_float4(0.f, 0.f, 0.f, 0.f);
        if (n < NN) v = reinterpret_cast<const float4*>(feat)[(size_t)n * 16 + (f4 & 15)];
        *reinterpret_cast<float4*>(&sF[nl * 68 + ic]) = v;
    }
    __syncthreads();

    const int to = t & 7;
    const int tn = t >> 3;

    float acc[4][8];
    #pragma unroll
    for (int j = 0; j < 4; ++j)
        #pragma unroll
        for (int m = 0; m < 8; ++m) acc[j][m] = 0.f;

    #pragma unroll 4
    for (int i0 = 0; i0 < DD; i0 += 4) {
        float wv[4][8];
        #pragma unroll
        for (int k = 0; k < 4; ++k) {
            float4 a = *reinterpret_cast<const float4*>(&sW[(i0 + k) * DD + to * 4]);
            float4 b = *reinterpret_cast<const float4*>(&sW[(i0 + k) * DD + 32 + to * 4]);
            wv[k][0] = a.x; wv[k][1] = a.y; wv[k][2] = a.z; wv[k][3] = a.w;
            wv[k][4] = b.x; wv[k][5] = b.y; wv[k][6] = b.z; wv[k][7] = b.w;
        }
        #pragma unroll
        for (int j = 0; j < 4; ++j) {
            float4 f = *reinterpret_cast<const float4*>(&sF[(tn + 32 * j) * 68 + i0]);
            float fv[4] = {f.x, f.y, f.z, f.w};
            #pragma unroll
            for (int k = 0; k < 4; ++k)
                #pragma unroll
                for (int m = 0; m < 8; ++m)
                    acc[j][m] = fmaf(fv[k], wv[k][m], acc[j][m]);
        }
    }

    if (r < RR) {
        #pragma unroll
        for (int j = 0; j < 4; ++j) {
            int n = nbase + tn + 32 * j;
            if (n < NN) {
                size_t row = ((size_t)r * NN + n) * DD;
                u32 p0 = f2bf_rn(acc[j][0]) | (f2bf_rn(acc[j][1]) << 16);
                u32 p1 = f2bf_rn(acc[j][2]) | (f2bf_rn(acc[j][3]) << 16);
                u32 p2 = f2bf_rn(acc[j][4]) | (f2bf_rn(acc[j][5]) << 16);
                u32 p3 = f2bf_rn(acc[j][6]) | (f2bf_rn(acc[j][7]) << 16);
                *reinterpret_cast<uint2*>(&xr[row + to * 4]) = make_uint2(p0, p1);
                *reinterpret_cast<uint2*>(&xr[row + 32 + to * 4]) = make_uint2(p2, p3);
            }
        }
    } else {
        #pragma unroll
        for (int j = 0; j < 4; ++j) {
            int n = nbase + tn + 32 * j;
            if (n < NN) {
                size_t row = (size_t)n * DD;
                *reinterpret_cast<float4*>(&out[row + to * 4]) =
                    make_float4(acc[j][0], acc[j][1], acc[j][2], acc[j][3]);
                *reinterpret_cast<float4*>(&out[row + 32 + to * 4]) =
                    make_float4(acc[j][4], acc[j][5], acc[j][6], acc[j][7]);
            }
        }
    }
}

// ---------------- dst-CSR build ----------------
__global__ __launch_bounds__(256)
void k_zero(int* __restrict__ p) {           // NPAD ints
    p[blockIdx.x * 256 + threadIdx.x] = 0;
}

__global__ __launch_bounds__(256)
void k_hist(const int* __restrict__ dst, int* __restrict__ count) {
    int e = blockIdx.x * 256 + threadIdx.x;
    if (e < EE) atomicAdd(&count[dst[e]], 1);
}

__global__ __launch_bounds__(256)
void k_blocksum(const int* __restrict__ count, int* __restrict__ bsum) {
    __shared__ int s[256];
    int t = threadIdx.x;
    s[t] = count[blockIdx.x * 256 + t];
    __syncthreads();
    #pragma unroll
    for (int off = 128; off > 0; off >>= 1) {
        if (t < off) s[t] += s[t + off];
        __syncthreads();
    }
    if (t == 0) bsum[blockIdx.x] = s[0];
}

__global__ __launch_bounds__(256)
void k_scanbase(const int* __restrict__ bsum, int* __restrict__ bbase) {
    __shared__ int s[256];
    int t = threadIdx.x;
    int v = (t < NBLK) ? bsum[t] : 0;
    s[t] = v;
    __syncthreads();
    #pragma unroll
    for (int off = 1; off < 256; off <<= 1) {
        int x = (t >= off) ? s[t - off] : 0;
        __syncthreads();
        s[t] += x;
        __syncthreads();
    }
    bbase[t] = s[t] - v;   // exclusive
}

__global__ __launch_bounds__(256)
void k_offsets(const int* __restrict__ count, const int* __restrict__ bbase,
               int* __restrict__ base, int* __restrict__ cursor) {
    __shared__ int s[256];
    int t = threadIdx.x;
    int i = blockIdx.x * 256 + t;
    int v = count[i];
    s[t] = v;
    __syncthreads();
    #pragma unroll
    for (int off = 1; off < 256; off <<= 1) {
        int x = (t >= off) ? s[t - off] : 0;
        __syncthreads();
        s[t] += x;
        __syncthreads();
    }
    int b = s[t] - v + bbase[blockIdx.x];
    base[i] = b;
    cursor[i] = b;
}

__global__ __launch_bounds__(256)
void k_scatter(const int* __restrict__ src, const int* __restrict__ dst,
               const int* __restrict__ etype, const float* __restrict__ norm,
               int* __restrict__ cursor, uint2* __restrict__ rec) {
    int e = blockIdx.x * 256 + threadIdx.x;
    if (e >= EE) return;
    int d = dst[e];
    int pos = atomicAdd(&cursor[d], 1);
    rec[pos] = make_uint2((u32)src[e] | ((u32)etype[e] << 16),
                          __float_as_uint(norm[e]));
}

// One wave per dst node: gather xr rows, accumulate in regs, fused +self +relu.
__global__ __launch_bounds__(256)
void k_agg(const int* __restrict__ base, const int* __restrict__ count,
           const uint2* __restrict__ rec, const u16* __restrict__ xr,
           float* __restrict__ out) {
    int n = (blockIdx.x * 256 + threadIdx.x) >> 6;
    int lane = threadIdx.x & 63;
    if (n >= NN) return;
    int st = base[n];
    int cnt = count[n];
    float acc = 0.f;
    int k = 0;
    for (; k + 2 <= cnt; k += 2) {
        uint2 r0 = rec[st + k];
        uint2 r1 = rec[st + k + 1];
        size_t row0 = ((size_t)(r0.x >> 16) * NN + (r0.x & 0xFFFFu)) * DD;
        size_t row1 = ((size_t)(r1.x >> 16) * NN + (r1.x & 0xFFFFu)) * DD;
        float v0 = __uint_as_float((u32)xr[row0 + lane] << 16);
        float v1 = __uint_as_float((u32)xr[row1 + lane] << 16);
        acc = fmaf(v0, __uint_as_float(r0.y), acc);
        acc = fmaf(v1, __uint_as_float(r1.y), acc);
    }
    if (k < cnt) {
        uint2 r0 = rec[st + k];
        size_t row0 = ((size_t)(r0.x >> 16) * NN + (r0.x & 0xFFFFu)) * DD;
        float v0 = __uint_as_float((u32)xr[row0 + lane] << 16);
        acc = fmaf(v0, __uint_as_float(r0.y), acc);
    }
    size_t o = (size_t)n * DD + lane;
    out[o] = fmaxf(out[o] + acc, 0.f);
}

// ---------------- fallbacks (R1 path, passing) ----------------
__global__ __launch_bounds__(256)
void k_edges(const int* __restrict__ src, const int* __restrict__ dst,
             const int* __restrict__ etype, const float* __restrict__ norm,
             const u16* __restrict__ xr, float* __restrict__ out) {
    int gtid = blockIdx.x * 256 + threadIdx.x;
    int e = gtid >> 4;
    int l = gtid & 15;
    if (e >= EE) return;
    int s = src[e];
    int d = dst[e];
    int rt = etype[e];
    float nm = norm[e];
    size_t row = ((size_t)rt * NN + s) * DD;
    uint2 u = *reinterpret_cast<const uint2*>(&xr[row + l * 4]);
    float f0 = __uint_as_float((u.x & 0xFFFFu) << 16);
    float f1 = __uint_as_float(u.x & 0xFFFF0000u);
    float f2 = __uint_as_float((u.y & 0xFFFFu) << 16);
    float f3 = __uint_as_float(u.y & 0xFFFF0000u);
    float* op = out + (size_t)d * DD + l * 4;
    atomicAdd(op + 0, f0 * nm);
    atomicAdd(op + 1, f1 * nm);
    atomicAdd(op + 2, f2 * nm);
    atomicAdd(op + 3, f3 * nm);
}

__global__ void k_makeW(const float* __restrict__ weight,
                        const float* __restrict__ w_comp,
                        float* __restrict__ W) {
    int f = blockIdx.x * 256 + threadIdx.x;
    if (f >= RR * 4096) return;
    int r = f >> 12;
    int io = f & 4095;
    float v = 0.f;
    #pragma unroll
    for (int b = 0; b < BB; ++b) v += w_comp[r * BB + b] * weight[b * 4096 + io];
    W[f] = v;
}

__global__ __launch_bounds__(256)
void k_edges_direct(const int* __restrict__ src, const int* __restrict__ dst,
                    const int* __restrict__ etype, const float* __restrict__ norm,
                    const float* __restrict__ feat, const float* __restrict__ W,
                    float* __restrict__ out) {
    int gtid = blockIdx.x * 256 + threadIdx.x;
    int e = gtid >> 6;
    int lane = gtid & 63;
    if (e >= EE) return;
    int s = src[e];
    int d = dst[e];
    int rt = etype[e];
    float nm = norm[e];
    const float* fr = feat + (size_t)s * DD;
    const float* Wr = W + (size_t)rt * 4096;
    float acc = 0.f;
    #pragma unroll
    for (int i = 0; i < DD; ++i) acc = fmaf(fr[i], Wr[i * DD + lane], acc);
    atomicAdd(&out[(size_t)d * DD + lane], acc * nm);
}

__global__ __launch_bounds__(256)
void k_relu(float* __restrict__ out) {
    int i = blockIdx.x * 256 + threadIdx.x;
    float4* p = reinterpret_cast<float4*>(out);
    float4 v = p[i];
    v.x = fmaxf(v.x, 0.f);
    v.y = fmaxf(v.y, 0.f);
    v.z = fmaxf(v.z, 0.f);
    v.w = fmaxf(v.w, 0.f);
    p[i] = v;
}

extern "C" void kernel_launch(void* const* d_in, const int* in_sizes, int n_in,
                              void* d_out, int out_size, void* d_ws, size_t ws_size,
                              hipStream_t stream) {
    const float* feat   = (const float*)d_in[0];
    const int*   src    = (const int*)d_in[1];
    const int*   dst    = (const int*)d_in[2];
    const int*   etype  = (const int*)d_in[3];
    const float* norm   = (const float*)d_in[4];
    const float* weight = (const float*)d_in[5];
    const float* w_comp = (const float*)d_in[6];
    const float* self_w = (const float*)d_in[7];
    float* out = (float*)d_out;

    // ws layout (full path)
    const size_t off_xr   = 0;
    const size_t sz_xr    = (size_t)RR * NN * DD * sizeof(u16);   // 64,000,000
    const size_t off_cnt  = off_xr + sz_xr;                        // NPAD ints
    const size_t off_bsum = off_cnt + (size_t)NPAD * 4;            // 256 ints
    const size_t off_bbas = off_bsum + 1024;                       // 256 ints
    const size_t off_base = off_bbas + 1024;                       // NPAD ints
    const size_t off_cur  = off_base + (size_t)NPAD * 4;           // NPAD ints
    const size_t off_rec  = off_cur + (size_t)NPAD * 4;            // EE uint2
    const size_t need_full = off_rec + (size_t)EE * 8;             // ~71.0 MB

    dim3 blk(256);
    char* ws = (char*)d_ws;

    if (ws_size >= need_full) {
        u16*  xr     = (u16*)(ws + off_xr);
        int*  count  = (int*)(ws + off_cnt);
        int*  bsum   = (int*)(ws + off_bsum);
        int*  bbase  = (int*)(ws + off_bbas);
        int*  basep  = (int*)(ws + off_base);
        int*  cursor = (int*)(ws + off_cur);
        uint2* rec   = (uint2*)(ws + off_rec);

        k_transform<<<dim3(391, RR + 1), blk, 0, stream>>>(feat, weight, w_comp,
                                                           self_w, xr, out, 0);
        k_zero<<<dim3(NBLK), blk, 0, stream>>>(count);
        k_hist<<<dim3((EE + 255) / 256), blk, 0, stream>>>(dst, count);
        k_blocksum<<<dim3(NBLK), blk, 0, stream>>>(count, bsum);
        k_scanbase<<<dim3(1), blk, 0, stream>>>(bsum, bbase);
        k_offsets<<<dim3(NBLK), blk, 0, stream>>>(count, bbase, basep, cursor);
        k_scatter<<<dim3((EE + 255) / 256), blk, 0, stream>>>(src, dst, etype, norm,
                                                              cursor, rec);
        k_agg<<<dim3((NN * 64 + 255) / 256), blk, 0, stream>>>(basep, count, rec, xr, out);
    } else if (ws_size >= sz_xr) {
        u16* xr = (u16*)d_ws;
        k_transform<<<dim3(391, RR + 1), blk, 0, stream>>>(feat, weight, w_comp,
                                                           self_w, xr, out, 0);
        k_edges<<<dim3(EE * 16 / 256), blk, 0, stream>>>(src, dst, etype, norm, xr, out);
        k_relu<<<dim3(NN * DD / 4 / 256), blk, 0, stream>>>(out);
    } else {
        k_transform<<<dim3(391, 1), blk, 0, stream>>>(feat, weight, w_comp,
                                                      self_w, (u16*)d_ws, out, RR);
        float* W = (float*)d_ws;
        k_makeW<<<dim3(160), blk, 0, stream>>>(weight, w_comp, W);
        k_edges_direct<<<dim3(EE * 64 / 256), blk, 0, stream>>>(src, dst, etype, norm,
                                                                feat, W, out);
        k_relu<<<dim3(NN * DD / 4 / 256), blk, 0, stream>>>(out);
    }
}

// Round 3
// 252.270 us; speedup vs baseline: 3.3132x; 1.1700x over previous
//
#include <hip/hip_runtime.h>
#include <hip/hip_bf16.h>
#include <stdint.h>

#define NN 50000
#define EE 800000
#define DD 64
#define RR 10
#define BB 4
#define NPAD 50176          // 196*256, padded node count for scan
#define NBLK 196

using u16 = unsigned short;
using u32 = unsigned int;

typedef short v8s __attribute__((ext_vector_type(8)));   // 8 bf16 (4 VGPRs)
typedef float v4f __attribute__((ext_vector_type(4)));   // MFMA accumulator

__device__ __forceinline__ u32 f2bf_rn(float x) {
    u32 u = __float_as_uint(x);
    return (u + 0x7FFFu + ((u >> 16) & 1u)) >> 16;
}
__device__ __forceinline__ u32 pack2bf(float a, float b) {
    return f2bf_rn(a) | (f2bf_rn(b) << 16);
}

// ---------------- feat fp32 -> bf16 (into rec region, dead until scatter) ----
__global__ __launch_bounds__(256)
void k_cast(const float* __restrict__ feat, u16* __restrict__ featb) {
    int i = blockIdx.x * 256 + threadIdx.x;     // one uint4 (8 elems) each
    if (i >= NN * DD / 8) return;
    float4 f0 = reinterpret_cast<const float4*>(feat)[2 * i];
    float4 f1 = reinterpret_cast<const float4*>(feat)[2 * i + 1];
    uint4 o;
    o.x = pack2bf(f0.x, f0.y);
    o.y = pack2bf(f0.z, f0.w);
    o.z = pack2bf(f1.x, f1.y);
    o.w = pack2bf(f1.z, f1.w);
    reinterpret_cast<uint4*>(featb)[i] = o;
}

// ---------------- MFMA transform: 128 nodes x 64 outs per block ------------
// blockIdx.y = r: r<RR -> bf16 xr[r*NN+n]; r==RR -> self-loop, fp32 out.
__global__ __launch_bounds__(256, 2)
void k_transform_mfma(const u16* __restrict__ featb,
                      const float* __restrict__ weight,
                      const float* __restrict__ w_comp,
                      const float* __restrict__ self_w,
                      u16* __restrict__ xr, float* __restrict__ out) {
    __shared__ u16 sWt[64 * 72];      // Wt[n][k], stride 72 breaks bank conflicts
    __shared__ float sD[128 * 68];    // epilogue transpose buffer
    const int t = threadIdx.x;
    const int r = blockIdx.y;
    const int nbase = blockIdx.x * 128;

    // Build Wt[n][k] = W_r[k][n] in bf16 (basis combo, or self-loop weight).
    if (r < RR) {
        const float c0 = w_comp[r * BB + 0];
        const float c1 = w_comp[r * BB + 1];
        const float c2 = w_comp[r * BB + 2];
        const float c3 = w_comp[r * BB + 3];
        #pragma unroll
        for (int qq = 0; qq < 16; ++qq) {
            int idx = t + 256 * qq;          // 0..4095
            int n = idx & 63, k = idx >> 6;
            float v = c0 * weight[k * 64 + n] + c1 * weight[4096 + k * 64 + n] +
                      c2 * weight[8192 + k * 64 + n] + c3 * weight[12288 + k * 64 + n];
            sWt[n * 72 + k] = (u16)f2bf_rn(v);
        }
    } else {
        #pragma unroll
        for (int qq = 0; qq < 16; ++qq) {
            int idx = t + 256 * qq;
            int n = idx & 63, k = idx >> 6;
            sWt[n * 72 + k] = (u16)f2bf_rn(self_w[k * 64 + n]);
        }
    }
    __syncthreads();

    const int wv = t >> 6;      // wave 0..3 -> rows wv*32..wv*32+31
    const int L = t & 63;
    const int q = L >> 4;       // quad
    const int c = L & 15;

    // B frags from LDS: B[k=q*8+j][n=c] -> Wt[nt*16+c][kh*32+q*8 ..+7]
    v8s bf[4][2];
    #pragma unroll
    for (int nt = 0; nt < 4; ++nt)
        #pragma unroll
        for (int kh = 0; kh < 2; ++kh)
            bf[nt][kh] = *reinterpret_cast<const v8s*>(&sWt[(nt * 16 + c) * 72 + kh * 32 + q * 8]);

    // A frags from global: A[m=c][k=q*8+j] -> featb row (nbase+wv*32+mt*16+c)
    v8s af[2][2];
    #pragma unroll
    for (int mt = 0; mt < 2; ++mt) {
        int g = nbase + wv * 32 + mt * 16 + c;
        const u16* p = featb + (size_t)((g < NN) ? g : 0) * DD;
        #pragma unroll
        for (int kh = 0; kh < 2; ++kh)
            af[mt][kh] = *reinterpret_cast<const v8s*>(p + kh * 32 + q * 8);
    }

    v4f acc[2][4];
    #pragma unroll
    for (int mt = 0; mt < 2; ++mt)
        #pragma unroll
        for (int nt = 0; nt < 4; ++nt) {
            acc[mt][nt] = (v4f)(0.f);
            #pragma unroll
            for (int kh = 0; kh < 2; ++kh)
                acc[mt][nt] = __builtin_amdgcn_mfma_f32_16x16x32_bf16(
                    af[mt][kh], bf[nt][kh], acc[mt][nt], 0, 0, 0);
        }

    // C/D layout: D[m=q*4+reg][n=c] -> scatter into sD
    #pragma unroll
    for (int mt = 0; mt < 2; ++mt) {
        int mrow = wv * 32 + mt * 16 + q * 4;
        #pragma unroll
        for (int nt = 0; nt < 4; ++nt)
            #pragma unroll
            for (int rg = 0; rg < 4; ++rg)
                sD[(mrow + rg) * 68 + nt * 16 + c] = acc[mt][nt][rg];
    }
    __syncthreads();

    // Coalesced writeout: thread t -> row t>>1, cols (t&1)*32 .. +31
    const int row = t >> 1;
    const int cb = (t & 1) * 32;
    const int g = nbase + row;
    if (g < NN) {
        const float* sp = &sD[row * 68 + cb];
        if (r < RR) {
            u16* dp = xr + ((size_t)r * NN + g) * DD + cb;
            #pragma unroll
            for (int j = 0; j < 4; ++j) {
                float4 f0 = *reinterpret_cast<const float4*>(sp + j * 8);
                float4 f1 = *reinterpret_cast<const float4*>(sp + j * 8 + 4);
                uint4 o;
                o.x = pack2bf(f0.x, f0.y);
                o.y = pack2bf(f0.z, f0.w);
                o.z = pack2bf(f1.x, f1.y);
                o.w = pack2bf(f1.z, f1.w);
                *reinterpret_cast<uint4*>(dp + j * 8) = o;
            }
        } else {
            float* dp = out + (size_t)g * DD + cb;
            #pragma unroll
            for (int j = 0; j < 8; ++j)
                *reinterpret_cast<float4*>(dp + j * 4) =
                    *reinterpret_cast<const float4*>(sp + j * 4);
        }
    }
}

// ---------------- dst-CSR build ----------------
__global__ __launch_bounds__(256)
void k_hist(const int* __restrict__ dst, int* __restrict__ count) {
    int e = blockIdx.x * 256 + threadIdx.x;
    if (e < EE) atomicAdd(&count[dst[e]], 1);
}

__global__ __launch_bounds__(256)
void k_blocksum(const int* __restrict__ count, int* __restrict__ bsum) {
    __shared__ int s[256];
    int t = threadIdx.x;
    s[t] = count[blockIdx.x * 256 + t];
    __syncthreads();
    #pragma unroll
    for (int off = 128; off > 0; off >>= 1) {
        if (t < off) s[t] += s[t + off];
        __syncthreads();
    }
    if (t == 0) bsum[blockIdx.x] = s[0];
}

__global__ __launch_bounds__(256)
void k_scanbase(const int* __restrict__ bsum, int* __restrict__ bbase) {
    __shared__ int s[256];
    int t = threadIdx.x;
    int v = (t < NBLK) ? bsum[t] : 0;
    s[t] = v;
    __syncthreads();
    #pragma unroll
    for (int off = 1; off < 256; off <<= 1) {
        int x = (t >= off) ? s[t - off] : 0;
        __syncthreads();
        s[t] += x;
        __syncthreads();
    }
    bbase[t] = s[t] - v;   // exclusive
}

__global__ __launch_bounds__(256)
void k_offsets(const int* __restrict__ count, const int* __restrict__ bbase,
               int* __restrict__ base, int* __restrict__ cursor) {
    __shared__ int s[256];
    int t = threadIdx.x;
    int i = blockIdx.x * 256 + t;
    int v = count[i];
    s[t] = v;
    __syncthreads();
    #pragma unroll
    for (int off = 1; off < 256; off <<= 1) {
        int x = (t >= off) ? s[t - off] : 0;
        __syncthreads();
        s[t] += x;
        __syncthreads();
    }
    int b = s[t] - v + bbase[blockIdx.x];
    base[i] = b;
    cursor[i] = b;
}

__global__ __launch_bounds__(256)
void k_scatter(const int* __restrict__ src, const int* __restrict__ dst,
               const int* __restrict__ etype, const float* __restrict__ norm,
               int* __restrict__ cursor, uint2* __restrict__ rec) {
    int e = blockIdx.x * 256 + threadIdx.x;
    if (e >= EE) return;
    int d = dst[e];
    int pos = atomicAdd(&cursor[d], 1);
    rec[pos] = make_uint2((u32)src[e] | ((u32)etype[e] << 16),
                          __float_as_uint(norm[e]));
}

// One wave per dst node; lane-halves own alternate edges; uint (2 cols) loads.
__global__ __launch_bounds__(256)
void k_agg(const int* __restrict__ base, const int* __restrict__ count,
           const uint2* __restrict__ rec, const u16* __restrict__ xr,
           float* __restrict__ out) {
    int n = (blockIdx.x * 256 + threadIdx.x) >> 6;
    int L = threadIdx.x & 63;
    if (n >= NN) return;
    const int h = L >> 5;        // edge-of-pair
    const int c = L & 31;        // col pair: cols 2c, 2c+1
    int st = base[n];
    int cnt = count[n];
    float a0 = 0.f, a1 = 0.f;
    int k = 0;
    for (; k + 4 <= cnt; k += 4) {
        uint2 r0 = rec[st + k + h];
        uint2 r1 = rec[st + k + 2 + h];
        size_t row0 = ((size_t)(r0.x >> 16) * NN + (r0.x & 0xFFFFu)) * DD;
        size_t row1 = ((size_t)(r1.x >> 16) * NN + (r1.x & 0xFFFFu)) * DD;
        u32 u0 = *reinterpret_cast<const u32*>(&xr[row0 + 2 * c]);
        u32 u1 = *reinterpret_cast<const u32*>(&xr[row1 + 2 * c]);
        float n0 = __uint_as_float(r0.y);
        float n1 = __uint_as_float(r1.y);
        a0 = fmaf(__uint_as_float((u0 & 0xFFFFu) << 16), n0, a0);
        a1 = fmaf(__uint_as_float(u0 & 0xFFFF0000u), n0, a1);
        a0 = fmaf(__uint_as_float((u1 & 0xFFFFu) << 16), n1, a0);
        a1 = fmaf(__uint_as_float(u1 & 0xFFFF0000u), n1, a1);
    }
    for (int kk = k + h; kk < cnt; kk += 2) {
        uint2 r0 = rec[st + kk];
        size_t row0 = ((size_t)(r0.x >> 16) * NN + (r0.x & 0xFFFFu)) * DD;
        u32 u0 = *reinterpret_cast<const u32*>(&xr[row0 + 2 * c]);
        float n0 = __uint_as_float(r0.y);
        a0 = fmaf(__uint_as_float((u0 & 0xFFFFu) << 16), n0, a0);
        a1 = fmaf(__uint_as_float(u0 & 0xFFFF0000u), n0, a1);
    }
    a0 += __shfl_xor(a0, 32);
    a1 += __shfl_xor(a1, 32);
    if (h == 0) {
        size_t o = (size_t)n * DD + 2 * c;
        float2 v = *reinterpret_cast<const float2*>(&out[o]);
        v.x = fmaxf(v.x + a0, 0.f);
        v.y = fmaxf(v.y + a1, 0.f);
        *reinterpret_cast<float2*>(&out[o]) = v;
    }
}

// ---------------- fallbacks (R1/R2 paths) ----------------
__global__ __launch_bounds__(256, 3)
void k_transform(const float* __restrict__ feat,
                 const float* __restrict__ weight,
                 const float* __restrict__ w_comp,
                 const float* __restrict__ self_w,
                 u16* __restrict__ xr,
                 float* __restrict__ out,
                 int rbase) {
    __shared__ float sW[DD * DD];
    __shared__ float sF[128 * 68];
    const int t = threadIdx.x;
    const int r = blockIdx.y + rbase;
    const int nbase = blockIdx.x * 128;

    if (r < RR) {
        const float c0 = w_comp[r * BB + 0];
        const float c1 = w_comp[r * BB + 1];
        const float c2 = w_comp[r * BB + 2];
        const float c3 = w_comp[r * BB + 3];
        #pragma unroll
        for (int qq = 0; qq < 16; ++qq) {
            int f = t + 256 * qq;
            sW[f] = c0 * weight[f] + c1 * weight[4096 + f] +
                    c2 * weight[8192 + f] + c3 * weight[12288 + f];
        }
    } else {
        #pragma unroll
        for (int qq = 0; qq < 16; ++qq) {
            int f = t + 256 * qq;
            sW[f] = self_w[f];
        }
    }

    #pragma unroll
    for (int qq = 0; qq < 8; ++qq) {
        int f4 = qq * 256 + t;
        int nl = f4 >> 4;
        int ic = (f4 & 15) << 2;
        int n = nbase + nl;
        float4 v = make_float4(0.f, 0.f, 0.f, 0.f);
        if (n < NN) v = reinterpret_cast<const float4*>(feat)[(size_t)n * 16 + (f4 & 15)];
        *reinterpret_cast<float4*>(&sF[nl * 68 + ic]) = v;
    }
    __syncthreads();

    const int to = t & 7;
    const int tn = t >> 3;

    float acc[4][8];
    #pragma unroll
    for (int j = 0; j < 4; ++j)
        #pragma unroll
        for (int m = 0; m < 8; ++m) acc[j][m] = 0.f;

    #pragma unroll 4
    for (int i0 = 0; i0 < DD; i0 += 4) {
        float wv[4][8];
        #pragma unroll
        for (int kq = 0; kq < 4; ++kq) {
            float4 a = *reinterpret_cast<const float4*>(&sW[(i0 + kq) * DD + to * 4]);
            float4 b = *reinterpret_cast<const float4*>(&sW[(i0 + kq) * DD + 32 + to * 4]);
            wv[kq][0] = a.x; wv[kq][1] = a.y; wv[kq][2] = a.z; wv[kq][3] = a.w;
            wv[kq][4] = b.x; wv[kq][5] = b.y; wv[kq][6] = b.z; wv[kq][7] = b.w;
        }
        #pragma unroll
        for (int j = 0; j < 4; ++j) {
            float4 f = *reinterpret_cast<const float4*>(&sF[(tn + 32 * j) * 68 + i0]);
            float fv[4] = {f.x, f.y, f.z, f.w};
            #pragma unroll
            for (int kq = 0; kq < 4; ++kq)
                #pragma unroll
                for (int m = 0; m < 8; ++m)
                    acc[j][m] = fmaf(fv[kq], wv[kq][m], acc[j][m]);
        }
    }

    if (r < RR) {
        #pragma unroll
        for (int j = 0; j < 4; ++j) {
            int n = nbase + tn + 32 * j;
            if (n < NN) {
                size_t row = ((size_t)r * NN + n) * DD;
                u32 p0 = pack2bf(acc[j][0], acc[j][1]);
                u32 p1 = pack2bf(acc[j][2], acc[j][3]);
                u32 p2 = pack2bf(acc[j][4], acc[j][5]);
                u32 p3 = pack2bf(acc[j][6], acc[j][7]);
                *reinterpret_cast<uint2*>(&xr[row + to * 4]) = make_uint2(p0, p1);
                *reinterpret_cast<uint2*>(&xr[row + 32 + to * 4]) = make_uint2(p2, p3);
            }
        }
    } else {
        #pragma unroll
        for (int j = 0; j < 4; ++j) {
            int n = nbase + tn + 32 * j;
            if (n < NN) {
                size_t row = (size_t)n * DD;
                *reinterpret_cast<float4*>(&out[row + to * 4]) =
                    make_float4(acc[j][0], acc[j][1], acc[j][2], acc[j][3]);
                *reinterpret_cast<float4*>(&out[row + 32 + to * 4]) =
                    make_float4(acc[j][4], acc[j][5], acc[j][6], acc[j][7]);
            }
        }
    }
}

__global__ __launch_bounds__(256)
void k_edges(const int* __restrict__ src, const int* __restrict__ dst,
             const int* __restrict__ etype, const float* __restrict__ norm,
             const u16* __restrict__ xr, float* __restrict__ out) {
    int gtid = blockIdx.x * 256 + threadIdx.x;
    int e = gtid >> 4;
    int l = gtid & 15;
    if (e >= EE) return;
    int s = src[e];
    int d = dst[e];
    int rt = etype[e];
    float nm = norm[e];
    size_t row = ((size_t)rt * NN + s) * DD;
    uint2 u = *reinterpret_cast<const uint2*>(&xr[row + l * 4]);
    float f0 = __uint_as_float((u.x & 0xFFFFu) << 16);
    float f1 = __uint_as_float(u.x & 0xFFFF0000u);
    float f2 = __uint_as_float((u.y & 0xFFFFu) << 16);
    float f3 = __uint_as_float(u.y & 0xFFFF0000u);
    float* op = out + (size_t)d * DD + l * 4;
    atomicAdd(op + 0, f0 * nm);
    atomicAdd(op + 1, f1 * nm);
    atomicAdd(op + 2, f2 * nm);
    atomicAdd(op + 3, f3 * nm);
}

__global__ void k_makeW(const float* __restrict__ weight,
                        const float* __restrict__ w_comp,
                        float* __restrict__ W) {
    int f = blockIdx.x * 256 + threadIdx.x;
    if (f >= RR * 4096) return;
    int r = f >> 12;
    int io = f & 4095;
    float v = 0.f;
    #pragma unroll
    for (int b = 0; b < BB; ++b) v += w_comp[r * BB + b] * weight[b * 4096 + io];
    W[f] = v;
}

__global__ __launch_bounds__(256)
void k_edges_direct(const int* __restrict__ src, const int* __restrict__ dst,
                    const int* __restrict__ etype, const float* __restrict__ norm,
                    const float* __restrict__ feat, const float* __restrict__ W,
                    float* __restrict__ out) {
    int gtid = blockIdx.x * 256 + threadIdx.x;
    int e = gtid >> 6;
    int lane = gtid & 63;
    if (e >= EE) return;
    int s = src[e];
    int d = dst[e];
    int rt = etype[e];
    float nm = norm[e];
    const float* fr = feat + (size_t)s * DD;
    const float* Wr = W + (size_t)rt * 4096;
    float acc = 0.f;
    #pragma unroll
    for (int i = 0; i < DD; ++i) acc = fmaf(fr[i], Wr[i * DD + lane], acc);
    atomicAdd(&out[(size_t)d * DD + lane], acc * nm);
}

__global__ __launch_bounds__(256)
void k_relu(float* __restrict__ out) {
    int i = blockIdx.x * 256 + threadIdx.x;
    float4* p = reinterpret_cast<float4*>(out);
    float4 v = p[i];
    v.x = fmaxf(v.x, 0.f);
    v.y = fmaxf(v.y, 0.f);
    v.z = fmaxf(v.z, 0.f);
    v.w = fmaxf(v.w, 0.f);
    p[i] = v;
}

extern "C" void kernel_launch(void* const* d_in, const int* in_sizes, int n_in,
                              void* d_out, int out_size, void* d_ws, size_t ws_size,
                              hipStream_t stream) {
    const float* feat   = (const float*)d_in[0];
    const int*   src    = (const int*)d_in[1];
    const int*   dst    = (const int*)d_in[2];
    const int*   etype  = (const int*)d_in[3];
    const float* norm   = (const float*)d_in[4];
    const float* weight = (const float*)d_in[5];
    const float* w_comp = (const float*)d_in[6];
    const float* self_w = (const float*)d_in[7];
    float* out = (float*)d_out;

    // ws layout (full path); rec region doubles as feat_bf16 (both 6,400,000 B)
    const size_t off_xr   = 0;
    const size_t sz_xr    = (size_t)RR * NN * DD * sizeof(u16);   // 64,000,000
    const size_t off_cnt  = off_xr + sz_xr;
    const size_t off_bsum = off_cnt + (size_t)NPAD * 4;
    const size_t off_bbas = off_bsum + 1024;
    const size_t off_base = off_bbas + 1024;
    const size_t off_cur  = off_base + (size_t)NPAD * 4;
    const size_t off_rec  = off_cur + (size_t)NPAD * 4;           // 16B-aligned
    const size_t need_full = off_rec + (size_t)EE * 8;            // ~71.0 MB

    dim3 blk(256);
    char* ws = (char*)d_ws;

    if (ws_size >= need_full) {
        u16*  xr     = (u16*)(ws + off_xr);
        int*  count  = (int*)(ws + off_cnt);
        int*  bsum   = (int*)(ws + off_bsum);
        int*  bbase  = (int*)(ws + off_bbas);
        int*  basep  = (int*)(ws + off_base);
        int*  cursor = (int*)(ws + off_cur);
        uint2* rec   = (uint2*)(ws + off_rec);
        u16*  featb  = (u16*)(ws + off_rec);   // overlay: dead before k_scatter

        k_cast<<<dim3((NN * DD / 8 + 255) / 256), blk, 0, stream>>>(feat, featb);
        k_transform_mfma<<<dim3(391, RR + 1), blk, 0, stream>>>(featb, weight, w_comp,
                                                                self_w, xr, out);
        hipMemsetAsync(count, 0, (size_t)NPAD * 4, stream);
        k_hist<<<dim3((EE + 255) / 256), blk, 0, stream>>>(dst, count);
        k_blocksum<<<dim3(NBLK), blk, 0, stream>>>(count, bsum);
        k_scanbase<<<dim3(1), blk, 0, stream>>>(bsum, bbase);
        k_offsets<<<dim3(NBLK), blk, 0, stream>>>(count, bbase, basep, cursor);
        k_scatter<<<dim3((EE + 255) / 256), blk, 0, stream>>>(src, dst, etype, norm,
                                                              cursor, rec);
        k_agg<<<dim3((NN * 64 + 255) / 256), blk, 0, stream>>>(basep, count, rec, xr, out);
    } else if (ws_size >= sz_xr) {
        u16* xr = (u16*)d_ws;
        k_transform<<<dim3(391, RR + 1), blk, 0, stream>>>(feat, weight, w_comp,
                                                           self_w, xr, out, 0);
        k_edges<<<dim3(EE * 16 / 256), blk, 0, stream>>>(src, dst, etype, norm, xr, out);
        k_relu<<<dim3(NN * DD / 4 / 256), blk, 0, stream>>>(out);
    } else {
        k_transform<<<dim3(391, 1), blk, 0, stream>>>(feat, weight, w_comp,
                                                      self_w, (u16*)d_ws, out, RR);
        float* W = (float*)d_ws;
        k_makeW<<<dim3(160), blk, 0, stream>>>(weight, w_comp, W);
        k_edges_direct<<<dim3(EE * 64 / 256), blk, 0, stream>>>(src, dst, etype, norm,
                                                                feat, W, out);
        k_relu<<<dim3(NN * DD / 4 / 256), blk, 0, stream>>>(out);
    }
}